// Round 1
// baseline (131.590 us; speedup 1.0000x reference)
//
#include <hip/hip_runtime.h>
#include <hip/hip_bf16.h>
#include <stdint.h>

#define NB    4096
#define NROWS 8192
#define DIM   512
#define BM    128
#define BN    128
#define BK    32

typedef __attribute__((ext_vector_type(8))) short          bf16x8;
typedef __attribute__((ext_vector_type(4))) float          f32x4;
typedef __attribute__((ext_vector_type(8))) unsigned short u16x8;

__device__ __forceinline__ unsigned short f2bf(float f) {
  uint32_t u = __float_as_uint(f);
  u += 0x7fffu + ((u >> 16) & 1u);   // round-to-nearest-even
  return (unsigned short)(u >> 16);
}

__device__ __forceinline__ float bf2f(unsigned short h) {
  return __uint_as_float(((uint32_t)h) << 16);
}

__device__ __forceinline__ void gload_lds16(const void* g, void* l) {
  __builtin_amdgcn_global_load_lds(
      (const __attribute__((address_space(1))) void*)g,
      (__attribute__((address_space(3))) void*)l, 16, 0, 0);
}

// ---------------- Kernel 1: L2-normalize rows, write bf16 P [8192][512] ----
__global__ __launch_bounds__(256) void normalize_kernel(
    const float* __restrict__ zi, const float* __restrict__ zj,
    unsigned short* __restrict__ p) {
  int wave = threadIdx.x >> 6;
  int lane = threadIdx.x & 63;
  int row  = blockIdx.x * 4 + wave;          // 0..8191
  const float* src = (row < NB) ? (zi + (size_t)row * DIM)
                                : (zj + (size_t)(row - NB) * DIM);
  const float4* s4 = (const float4*)src;
  float4 a = s4[lane * 2];
  float4 b = s4[lane * 2 + 1];
  float v[8] = {a.x, a.y, a.z, a.w, b.x, b.y, b.z, b.w};
  float ss = 0.f;
#pragma unroll
  for (int j = 0; j < 8; ++j) ss += v[j] * v[j];
#pragma unroll
  for (int off = 32; off; off >>= 1) ss += __shfl_xor(ss, off);
  float inv = rsqrtf(ss);
  u16x8 h;
#pragma unroll
  for (int j = 0; j < 8; ++j) h[j] = f2bf(v[j] * inv);
  *(u16x8*)(p + (size_t)row * DIM + lane * 8) = h;
}

// ---------------- Kernel 2: fused S = 2*P*P^T -> exp -> row sums -----------
// 128x128 tile, BK=32, 4 waves (2x2), each wave 64x64 via 4x4 16x16x32 MFMA.
// LDS linear (global_load_lds); bank-conflict swizzle applied on the global
// SOURCE address and the ds_read address: chunk' = chunk ^ ((row>>1)&3).
__global__ __launch_bounds__(256) void simexp_kernel(
    const unsigned short* __restrict__ p, float* __restrict__ rowsum) {
  __shared__ unsigned short As[BM * BK];   // 8 KB
  __shared__ unsigned short Bs[BN * BK];   // 8 KB

  const int bi   = blockIdx.x;
  const int bj   = blockIdx.y;
  const int tid  = threadIdx.x;
  const int wave = tid >> 6;
  const int lane = tid & 63;
  const int wm   = wave >> 1;   // 0..1 : row half
  const int wn   = wave & 1;    // 0..1 : col half

  f32x4 acc[4][4] = {};

  // staging geometry: thread t covers row (t>>2) within a 64-row half, 16B chunk (t&3)
  const int srow   = tid >> 2;    // 0..63
  const int schunk = tid & 3;     // 0..3

  for (int k0 = 0; k0 < DIM; k0 += BK) {
#pragma unroll
    for (int h = 0; h < 2; ++h) {
      int r      = h * 64 + srow;
      int gchunk = schunk ^ ((r >> 1) & 3);          // pre-swizzled source
      const unsigned short* ga =
          p + (size_t)(bi * BM + r) * DIM + k0 + gchunk * 8;
      const unsigned short* gb =
          p + (size_t)(bj * BN + r) * DIM + k0 + gchunk * 8;
      void* lA = (char*)As + h * 4096 + wave * 1024;  // wave-uniform base
      void* lB = (char*)Bs + h * 4096 + wave * 1024;
      gload_lds16(ga, lA);
      gload_lds16(gb, lB);
    }
    __syncthreads();

    const int frow = lane & 15;
    const int kc   = lane >> 4;
    bf16x8 af[4], bf_[4];
#pragma unroll
    for (int m = 0; m < 4; ++m) {
      int row = wm * 64 + m * 16 + frow;
      int c   = kc ^ ((row >> 1) & 3);
      af[m] = *(const bf16x8*)((const char*)As + row * 64 + c * 16);
    }
#pragma unroll
    for (int n = 0; n < 4; ++n) {
      int row = wn * 64 + n * 16 + frow;
      int c   = kc ^ ((row >> 1) & 3);
      bf_[n] = *(const bf16x8*)((const char*)Bs + row * 64 + c * 16);
    }
#pragma unroll
    for (int m = 0; m < 4; ++m)
#pragma unroll
      for (int n = 0; n < 4; ++n)
        acc[m][n] = __builtin_amdgcn_mfma_f32_16x16x32_bf16(
            af[m], bf_[n], acc[m][n], 0, 0, 0);
    __syncthreads();
  }

  // epilogue: exp(2*s), skip diagonal, reduce across the 16 col-lanes, atomicAdd per row
  const int r4 = lane >> 4;
  const int cl = lane & 15;
#pragma unroll
  for (int m = 0; m < 4; ++m) {
#pragma unroll
    for (int r = 0; r < 4; ++r) {
      int grow = bi * BM + wm * 64 + m * 16 + r4 * 4 + r;
      float s = 0.f;
#pragma unroll
      for (int n = 0; n < 4; ++n) {
        int gcol = bj * BN + wn * 64 + n * 16 + cl;
        float e  = __expf(2.0f * acc[m][n][r]);
        s += (grow == gcol) ? 0.f : e;
      }
      s += __shfl_xor(s, 1);
      s += __shfl_xor(s, 2);
      s += __shfl_xor(s, 4);
      s += __shfl_xor(s, 8);
      if (cl == 0) atomicAdd(&rowsum[grow], s);
    }
  }
}

// ---------------- Kernel 3: sum of positives -------------------------------
// pos_i = 2*dot(p[i], p[i+NB]); total pos sum (over all 2B rows) = 4 * sum dot
__global__ __launch_bounds__(256) void pos_kernel(
    const unsigned short* __restrict__ p, float* __restrict__ possum) {
  __shared__ float ws4[4];
  int wave = threadIdx.x >> 6;
  int lane = threadIdx.x & 63;
  int i    = blockIdx.x * 4 + wave;   // 0..4095
  u16x8 ha = *(const u16x8*)(p + (size_t)i * DIM + lane * 8);
  u16x8 hb = *(const u16x8*)(p + (size_t)(i + NB) * DIM + lane * 8);
  float s = 0.f;
#pragma unroll
  for (int j = 0; j < 8; ++j) s += bf2f(ha[j]) * bf2f(hb[j]);
#pragma unroll
  for (int off = 32; off; off >>= 1) s += __shfl_xor(s, off);
  if (lane == 0) ws4[wave] = s;
  __syncthreads();
  if (threadIdx.x == 0)
    atomicAdd(possum, 4.0f * (ws4[0] + ws4[1] + ws4[2] + ws4[3]));
}

// ---------------- Kernel 4: finalize loss ----------------------------------
__global__ __launch_bounds__(256) void finalize_kernel(
    const float* __restrict__ rowsum, const float* __restrict__ possum,
    float* __restrict__ out) {
  __shared__ float ws4[4];
  int tid = threadIdx.x;
  float s = 0.f;
  for (int i = tid; i < NROWS; i += 256) s += logf(rowsum[i]);
#pragma unroll
  for (int off = 32; off; off >>= 1) s += __shfl_xor(s, off);
  if ((tid & 63) == 0) ws4[tid >> 6] = s;
  __syncthreads();
  if (tid == 0) {
    float t = ws4[0] + ws4[1] + ws4[2] + ws4[3];
    out[0] = (t - possum[0]) / (float)NROWS;
  }
}

extern "C" void kernel_launch(void* const* d_in, const int* in_sizes, int n_in,
                              void* d_out, int out_size, void* d_ws,
                              size_t ws_size, hipStream_t stream) {
  const float* zi = (const float*)d_in[0];
  const float* zj = (const float*)d_in[1];
  float* out      = (float*)d_out;

  char* ws              = (char*)d_ws;
  unsigned short* p     = (unsigned short*)ws;                       // 8 MB bf16
  float* rowsum         = (float*)(ws + (size_t)NROWS * DIM * 2);    // 32 KB
  float* possum         = rowsum + NROWS;                            // 4 B

  hipMemsetAsync(rowsum, 0, (NROWS + 1) * sizeof(float), stream);
  normalize_kernel<<<NROWS / 4, 256, 0, stream>>>(zi, zj, p);
  dim3 grid(NROWS / BM, NROWS / BN);
  simexp_kernel<<<grid, 256, 0, stream>>>(p, rowsum);
  pos_kernel<<<NB / 4, 256, 0, stream>>>(p, possum);
  finalize_kernel<<<1, 256, 0, stream>>>(rowsum, possum, out);
}

// Round 2
// 111.253 us; speedup vs baseline: 1.1828x; 1.1828x over previous
//
#include <hip/hip_runtime.h>
#include <hip/hip_bf16.h>
#include <stdint.h>

#define NB    4096
#define NROWS 8192
#define DIM   512
#define BM    128
#define BN    128
#define BK    32
#define TGRID 64                      // NROWS / BM
#define NTRI  (TGRID * (TGRID + 1) / 2)   // 2080

typedef __attribute__((ext_vector_type(8))) short          bf16x8;
typedef __attribute__((ext_vector_type(4))) float          f32x4;
typedef __attribute__((ext_vector_type(8))) unsigned short u16x8;

__device__ __forceinline__ unsigned short f2bf(float f) {
  uint32_t u = __float_as_uint(f);
  u += 0x7fffu + ((u >> 16) & 1u);   // round-to-nearest-even
  return (unsigned short)(u >> 16);
}

__device__ __forceinline__ float bf2f(unsigned short h) {
  return __uint_as_float(((uint32_t)h) << 16);
}

__device__ __forceinline__ void gload_lds16(const void* g, void* l) {
  __builtin_amdgcn_global_load_lds(
      (const __attribute__((address_space(1))) void*)g,
      (__attribute__((address_space(3))) void*)l, 16, 0, 0);
}

// ---- Kernel 1: normalize rows -> bf16 P, fused pos partials, zero rowsum --
// wave handles pair (i, i+NB) = (zi row i, zj row i); 1024 blocks x 256 thr
__global__ __launch_bounds__(256) void normalize_pos_kernel(
    const float* __restrict__ zi, const float* __restrict__ zj,
    unsigned short* __restrict__ p, float* __restrict__ rowsum,
    float* __restrict__ posp) {
  __shared__ float ws4[4];
  const int wave = threadIdx.x >> 6;
  const int lane = threadIdx.x & 63;
  const int i    = blockIdx.x * 4 + wave;          // 0..4095

  // fold rowsum zeroing into this kernel (stream-ordered before simexp)
  int gt = blockIdx.x * 256 + threadIdx.x;
  if (gt < NROWS) rowsum[gt] = 0.f;

  const float4* sa = (const float4*)(zi + (size_t)i * DIM);
  const float4* sb = (const float4*)(zj + (size_t)i * DIM);
  float4 a0 = sa[lane * 2], a1 = sa[lane * 2 + 1];
  float4 b0 = sb[lane * 2], b1 = sb[lane * 2 + 1];
  float va[8] = {a0.x, a0.y, a0.z, a0.w, a1.x, a1.y, a1.z, a1.w};
  float vb[8] = {b0.x, b0.y, b0.z, b0.w, b1.x, b1.y, b1.z, b1.w};
  float ssa = 0.f, ssb = 0.f;
#pragma unroll
  for (int j = 0; j < 8; ++j) { ssa += va[j] * va[j]; ssb += vb[j] * vb[j]; }
#pragma unroll
  for (int off = 32; off; off >>= 1) {
    ssa += __shfl_xor(ssa, off);
    ssb += __shfl_xor(ssb, off);
  }
  float inva = rsqrtf(ssa), invb = rsqrtf(ssb);
  u16x8 ha, hb;
#pragma unroll
  for (int j = 0; j < 8; ++j) { ha[j] = f2bf(va[j] * inva); hb[j] = f2bf(vb[j] * invb); }
  *(u16x8*)(p + (size_t)i * DIM + lane * 8)        = ha;
  *(u16x8*)(p + (size_t)(i + NB) * DIM + lane * 8) = hb;

  // positives partial: pos_i = 2*dot; counted twice over 2B rows -> 4*dot
  float d = 0.f;
#pragma unroll
  for (int j = 0; j < 8; ++j) d += bf2f(ha[j]) * bf2f(hb[j]);
#pragma unroll
  for (int off = 32; off; off >>= 1) d += __shfl_xor(d, off);
  if (lane == 0) ws4[wave] = d;
  __syncthreads();
  if (threadIdx.x == 0)
    posp[blockIdx.x] = 4.0f * (ws4[0] + ws4[1] + ws4[2] + ws4[3]);
}

// ---- Kernel 2: symmetric fused S = 2*P*P^T -> exp -> row+col sums ---------
// Upper-triangle tile grid (bi <= bj), 2080 blocks. Off-diag tiles feed both
// rowsum[row] and rowsum[col] (symmetry); diag tiles exclude the diagonal.
__global__ __launch_bounds__(256) void simexp_kernel(
    const unsigned short* __restrict__ p, float* __restrict__ rowsum) {
  __shared__ unsigned short As[BM * BK];   // 8 KB
  __shared__ unsigned short Bs[BN * BK];   // 8 KB

  // decode linear tile id -> (bi, bj), bi <= bj ; f(bi) = bi*(129-bi)/2
  const int t  = blockIdx.x;
  int bi = (int)((129.0f - sqrtf(16641.0f - 8.0f * (float)t)) * 0.5f);
  while ((bi + 1) * (129 - (bi + 1)) / 2 <= t) ++bi;
  while (bi * (129 - bi) / 2 > t) --bi;
  const int bj   = bi + (t - bi * (129 - bi) / 2);
  const bool diag = (bi == bj);

  const int tid  = threadIdx.x;
  const int wave = tid >> 6;
  const int lane = tid & 63;
  const int wm   = wave >> 1;   // 0..1 : row half
  const int wn   = wave & 1;    // 0..1 : col half

  f32x4 acc[4][4] = {};

  const int srow   = tid >> 2;    // 0..63
  const int schunk = tid & 3;     // 0..3

  for (int k0 = 0; k0 < DIM; k0 += BK) {
#pragma unroll
    for (int h = 0; h < 2; ++h) {
      int r      = h * 64 + srow;
      int gchunk = schunk ^ ((r >> 1) & 3);          // pre-swizzled source
      const unsigned short* ga =
          p + (size_t)(bi * BM + r) * DIM + k0 + gchunk * 8;
      const unsigned short* gb =
          p + (size_t)(bj * BN + r) * DIM + k0 + gchunk * 8;
      void* lA = (char*)As + h * 4096 + wave * 1024;  // wave-uniform base
      void* lB = (char*)Bs + h * 4096 + wave * 1024;
      gload_lds16(ga, lA);
      gload_lds16(gb, lB);
    }
    __syncthreads();

    const int frow = lane & 15;
    const int kc   = lane >> 4;
    bf16x8 af[4], bf_[4];
#pragma unroll
    for (int m = 0; m < 4; ++m) {
      int row = wm * 64 + m * 16 + frow;
      int c   = kc ^ ((row >> 1) & 3);
      af[m] = *(const bf16x8*)((const char*)As + row * 64 + c * 16);
    }
#pragma unroll
    for (int n = 0; n < 4; ++n) {
      int row = wn * 64 + n * 16 + frow;
      int c   = kc ^ ((row >> 1) & 3);
      bf_[n] = *(const bf16x8*)((const char*)Bs + row * 64 + c * 16);
    }
#pragma unroll
    for (int m = 0; m < 4; ++m)
#pragma unroll
      for (int n = 0; n < 4; ++n)
        acc[m][n] = __builtin_amdgcn_mfma_f32_16x16x32_bf16(
            af[m], bf_[n], acc[m][n], 0, 0, 0);
    __syncthreads();
  }

  // epilogue: e = exp(2s); rowsum[row] += e always; rowsum[col] += e if off-diag
  const int r4 = lane >> 4;   // C/D: col = lane&15, row = (lane>>4)*4 + reg
  const int cl = lane & 15;

  float rowpart[4][4];        // [m][r] in-lane partial over n-subtiles
  float colpart[4] = {0.f, 0.f, 0.f, 0.f};   // [n] in-lane partial over m,r

  if (diag) {
#pragma unroll
    for (int m = 0; m < 4; ++m)
#pragma unroll
      for (int r = 0; r < 4; ++r) {
        int grow = bi * BM + wm * 64 + m * 16 + r4 * 4 + r;
        float s = 0.f;
#pragma unroll
        for (int n = 0; n < 4; ++n) {
          int gcol = bj * BN + wn * 64 + n * 16 + cl;
          float e  = __expf(2.0f * acc[m][n][r]);
          s += (grow == gcol) ? 0.f : e;
        }
        rowpart[m][r] = s;
      }
  } else {
#pragma unroll
    for (int m = 0; m < 4; ++m)
#pragma unroll
      for (int r = 0; r < 4; ++r) {
        float s = 0.f;
#pragma unroll
        for (int n = 0; n < 4; ++n) {
          float e = __expf(2.0f * acc[m][n][r]);
          s += e;
          colpart[n] += e;
        }
        rowpart[m][r] = s;
      }
  }

  // row sums: reduce across the 16 col-lanes
#pragma unroll
  for (int m = 0; m < 4; ++m)
#pragma unroll
    for (int r = 0; r < 4; ++r) {
      float s = rowpart[m][r];
      s += __shfl_xor(s, 1);
      s += __shfl_xor(s, 2);
      s += __shfl_xor(s, 4);
      s += __shfl_xor(s, 8);
      if (cl == 0) {
        int grow = bi * BM + wm * 64 + m * 16 + r4 * 4 + r;
        atomicAdd(&rowsum[grow], s);
      }
    }

  // col sums (symmetry contribution): reduce across the 4 r4 lane-groups
  if (!diag) {
#pragma unroll
    for (int n = 0; n < 4; ++n) {
      float c = colpart[n];
      c += __shfl_xor(c, 16);
      c += __shfl_xor(c, 32);
      if (r4 == 0) {
        int gcol = bj * BN + wn * 64 + n * 16 + cl;
        atomicAdd(&rowsum[gcol], c);
      }
    }
  }
}

// ---- Kernel 3: finalize loss ---------------------------------------------
__global__ __launch_bounds__(256) void finalize_kernel(
    const float* __restrict__ rowsum, const float* __restrict__ posp,
    float* __restrict__ out) {
  __shared__ float ws4[4];
  int tid = threadIdx.x;
  float v = 0.f;
  for (int i = tid; i < NROWS; i += 256) v += logf(rowsum[i]);
  for (int i = tid; i < 1024; i += 256) v -= posp[i];
#pragma unroll
  for (int off = 32; off; off >>= 1) v += __shfl_xor(v, off);
  if ((tid & 63) == 0) ws4[tid >> 6] = v;
  __syncthreads();
  if (tid == 0)
    out[0] = (ws4[0] + ws4[1] + ws4[2] + ws4[3]) / (float)NROWS;
}

extern "C" void kernel_launch(void* const* d_in, const int* in_sizes, int n_in,
                              void* d_out, int out_size, void* d_ws,
                              size_t ws_size, hipStream_t stream) {
  const float* zi = (const float*)d_in[0];
  const float* zj = (const float*)d_in[1];
  float* out      = (float*)d_out;

  char* ws          = (char*)d_ws;
  unsigned short* p = (unsigned short*)ws;                        // 8 MB bf16
  float* rowsum     = (float*)(ws + (size_t)NROWS * DIM * 2);     // 32 KB
  float* posp       = rowsum + NROWS;                             // 4 KB

  normalize_pos_kernel<<<NB / 4, 256, 0, stream>>>(zi, zj, p, rowsum, posp);
  simexp_kernel<<<NTRI, 256, 0, stream>>>(p, rowsum);
  finalize_kernel<<<1, 256, 0, stream>>>(rowsum, posp, out);
}

// Round 3
// 107.121 us; speedup vs baseline: 1.2284x; 1.0386x over previous
//
#include <hip/hip_runtime.h>
#include <hip/hip_bf16.h>
#include <stdint.h>

#define NB    4096
#define NROWS 8192
#define DIM   512
#define BM    128
#define BN    128
#define BK    32
#define NKS   (DIM / BK)              // 16 K-steps
#define NBLK  2176                    // 8 XCDs x 272 (96 early-exit)

typedef __attribute__((ext_vector_type(8))) short          bf16x8;
typedef __attribute__((ext_vector_type(4))) float          f32x4;
typedef __attribute__((ext_vector_type(8))) unsigned short u16x8;

__device__ __forceinline__ unsigned short f2bf(float f) {
  uint32_t u = __float_as_uint(f);
  u += 0x7fffu + ((u >> 16) & 1u);   // round-to-nearest-even
  return (unsigned short)(u >> 16);
}

__device__ __forceinline__ float bf2f(unsigned short h) {
  return __uint_as_float(((uint32_t)h) << 16);
}

__device__ __forceinline__ void gload_lds16(const void* g, void* l) {
  __builtin_amdgcn_global_load_lds(
      (const __attribute__((address_space(1))) void*)g,
      (__attribute__((address_space(3))) void*)l, 16, 0, 0);
}

// ---- Kernel 1: normalize rows -> bf16 P, fused pos partials, zero rowsum --
__global__ __launch_bounds__(256) void normalize_pos_kernel(
    const float* __restrict__ zi, const float* __restrict__ zj,
    unsigned short* __restrict__ p, float* __restrict__ rowsum,
    float* __restrict__ posp) {
  __shared__ float ws4[4];
  const int wave = threadIdx.x >> 6;
  const int lane = threadIdx.x & 63;
  const int i    = blockIdx.x * 4 + wave;          // 0..4095

  int gt = blockIdx.x * 256 + threadIdx.x;
  if (gt < NROWS) rowsum[gt] = 0.f;

  const float4* sa = (const float4*)(zi + (size_t)i * DIM);
  const float4* sb = (const float4*)(zj + (size_t)i * DIM);
  float4 a0 = sa[lane * 2], a1 = sa[lane * 2 + 1];
  float4 b0 = sb[lane * 2], b1 = sb[lane * 2 + 1];
  float va[8] = {a0.x, a0.y, a0.z, a0.w, a1.x, a1.y, a1.z, a1.w};
  float vb[8] = {b0.x, b0.y, b0.z, b0.w, b1.x, b1.y, b1.z, b1.w};
  float ssa = 0.f, ssb = 0.f;
#pragma unroll
  for (int j = 0; j < 8; ++j) { ssa += va[j] * va[j]; ssb += vb[j] * vb[j]; }
#pragma unroll
  for (int off = 32; off; off >>= 1) {
    ssa += __shfl_xor(ssa, off);
    ssb += __shfl_xor(ssb, off);
  }
  float inva = rsqrtf(ssa), invb = rsqrtf(ssb);
  u16x8 ha, hb;
#pragma unroll
  for (int j = 0; j < 8; ++j) { ha[j] = f2bf(va[j] * inva); hb[j] = f2bf(vb[j] * invb); }
  *(u16x8*)(p + (size_t)i * DIM + lane * 8)        = ha;
  *(u16x8*)(p + (size_t)(i + NB) * DIM + lane * 8) = hb;

  float d = 0.f;
#pragma unroll
  for (int j = 0; j < 8; ++j) d += bf2f(ha[j]) * bf2f(hb[j]);
#pragma unroll
  for (int off = 32; off; off >>= 1) d += __shfl_xor(d, off);
  if (lane == 0) ws4[wave] = d;
  __syncthreads();
  if (threadIdx.x == 0)
    posp[blockIdx.x] = 4.0f * (ws4[0] + ws4[1] + ws4[2] + ws4[3]);
}

// ---- Kernel 2: symmetric fused S = 2*P*P^T -> exp -> row+col sums ---------
// Upper-triangle tile grid partitioned into 4x4 supertiles of 16x16 tiles.
// XCD x = blockIdx.x%8 owns one region (~4MB working set == its L2):
//   x<6 : full square (si,sj) in {(0,1),(0,2),(0,3),(1,2),(1,3),(2,3)}
//   x=6 : diagonal halves (0,0)+(1,1);  x=7 : (2,2)+(3,3)
// 2-phase double-buffered pipeline: STAGE(next) -> vmcnt(4) -> barrier ->
// ds_read(cur) -> lgkmcnt(0) -> barrier -> MFMA (loads in flight across bar).
__global__ __launch_bounds__(256) void simexp_kernel(
    const unsigned short* __restrict__ p, float* __restrict__ rowsum) {
  __shared__ unsigned short As[2][BM * BK];   // 2 x 8 KB
  __shared__ unsigned short Bs[2][BM * BK];   // 2 x 8 KB

  const int x = blockIdx.x & 7;          // XCD (round-robin heuristic)
  const int l = blockIdx.x >> 3;         // 0..271 local index
  int bi, bj;
  if (x < 6) {
    if (l >= 256) return;                // uniform early-exit, before barriers
    const int sqi[6] = {0, 0, 0, 1, 1, 2};
    const int sqj[6] = {1, 2, 3, 2, 3, 3};
    bi = sqi[x] * 16 + (l >> 4);
    bj = sqj[x] * 16 + (l & 15);
  } else {
    int s  = (x == 6) ? 0 : 2;
    int ll = l;
    if (ll >= 136) { ll -= 136; s += 1; }
    int i = 0;
    while ((i + 1) * (33 - (i + 1)) / 2 <= ll) ++i;
    int j = i + (ll - i * (33 - i) / 2);
    bi = s * 16 + i;
    bj = s * 16 + j;
  }
  const bool diag = (bi == bj);

  const int tid  = threadIdx.x;
  const int wave = tid >> 6;
  const int lane = tid & 63;
  const int wm   = wave >> 1;
  const int wn   = wave & 1;

  f32x4 acc[4][4] = {};

  const int srow   = tid >> 2;
  const int schunk = tid & 3;
  const unsigned short* pa = p + (size_t)(bi * BM) * DIM;
  const unsigned short* pb = p + (size_t)(bj * BN) * DIM;

  const int frow = lane & 15;
  const int kc   = lane >> 4;

  // precompute ds_read byte offsets (swizzled), invariant over K
  int offA[4], offB[4];
#pragma unroll
  for (int m = 0; m < 4; ++m) {
    int row = wm * 64 + m * 16 + frow;
    offA[m] = row * 64 + (kc ^ ((row >> 1) & 3)) * 16;
  }
#pragma unroll
  for (int n = 0; n < 4; ++n) {
    int row = wn * 64 + n * 16 + frow;
    offB[n] = row * 64 + (kc ^ ((row >> 1) & 3)) * 16;
  }

#define STAGE(buf, k0)                                                        \
  {                                                                           \
    _Pragma("unroll")                                                         \
    for (int h = 0; h < 2; ++h) {                                             \
      int r      = h * 64 + srow;                                             \
      int gchunk = schunk ^ ((r >> 1) & 3);                                   \
      gload_lds16(pa + (size_t)r * DIM + (k0) + gchunk * 8,                   \
                  (char*)As[buf] + h * 4096 + wave * 1024);                   \
      gload_lds16(pb + (size_t)r * DIM + (k0) + gchunk * 8,                   \
                  (char*)Bs[buf] + h * 4096 + wave * 1024);                   \
    }                                                                         \
  }

#define LOAD_FRAGS(buf)                                                       \
  bf16x8 af[4], bf_[4];                                                       \
  {                                                                           \
    _Pragma("unroll")                                                         \
    for (int m = 0; m < 4; ++m)                                               \
      af[m] = *(const bf16x8*)((const char*)As[buf] + offA[m]);               \
    _Pragma("unroll")                                                         \
    for (int n = 0; n < 4; ++n)                                               \
      bf_[n] = *(const bf16x8*)((const char*)Bs[buf] + offB[n]);              \
  }

#define DO_MFMA()                                                             \
  {                                                                           \
    _Pragma("unroll")                                                         \
    for (int m = 0; m < 4; ++m)                                               \
      _Pragma("unroll")                                                       \
      for (int n = 0; n < 4; ++n)                                             \
        acc[m][n] = __builtin_amdgcn_mfma_f32_16x16x32_bf16(                  \
            af[m], bf_[n], acc[m][n], 0, 0, 0);                               \
  }

  int cur = 0;
  STAGE(0, 0);
  for (int t = 0; t < NKS - 1; ++t) {
    STAGE(cur ^ 1, (t + 1) * BK);
    asm volatile("s_waitcnt vmcnt(4)" ::: "memory");  // cur's 4 loads landed
    __builtin_amdgcn_s_barrier();                     // all waves' loads in
    LOAD_FRAGS(cur);
    asm volatile("s_waitcnt lgkmcnt(0)" ::: "memory");
    __builtin_amdgcn_s_barrier();                     // reads done -> safe ovw
    DO_MFMA();
    cur ^= 1;
  }
  asm volatile("s_waitcnt vmcnt(0)" ::: "memory");
  __builtin_amdgcn_s_barrier();
  {
    LOAD_FRAGS(cur);
    asm volatile("s_waitcnt lgkmcnt(0)" ::: "memory");
    DO_MFMA();
  }

  // epilogue: e = exp(2s); rowsum[row] += e; rowsum[col] += e if off-diag
  const int r4 = lane >> 4;   // C/D: col = lane&15, row = (lane>>4)*4 + reg
  const int cl = lane & 15;

  float rowpart[4][4];
  float colpart[4] = {0.f, 0.f, 0.f, 0.f};

  if (diag) {
#pragma unroll
    for (int m = 0; m < 4; ++m)
#pragma unroll
      for (int r = 0; r < 4; ++r) {
        int grow = bi * BM + wm * 64 + m * 16 + r4 * 4 + r;
        float s = 0.f;
#pragma unroll
        for (int n = 0; n < 4; ++n) {
          int gcol = bj * BN + wn * 64 + n * 16 + cl;
          float e  = __expf(2.0f * acc[m][n][r]);
          s += (grow == gcol) ? 0.f : e;
        }
        rowpart[m][r] = s;
      }
  } else {
#pragma unroll
    for (int m = 0; m < 4; ++m)
#pragma unroll
      for (int r = 0; r < 4; ++r) {
        float s = 0.f;
#pragma unroll
        for (int n = 0; n < 4; ++n) {
          float e = __expf(2.0f * acc[m][n][r]);
          s += e;
          colpart[n] += e;
        }
        rowpart[m][r] = s;
      }
  }

#pragma unroll
  for (int m = 0; m < 4; ++m)
#pragma unroll
    for (int r = 0; r < 4; ++r) {
      float s = rowpart[m][r];
      s += __shfl_xor(s, 1);
      s += __shfl_xor(s, 2);
      s += __shfl_xor(s, 4);
      s += __shfl_xor(s, 8);
      if (cl == 0) {
        int grow = bi * BM + wm * 64 + m * 16 + r4 * 4 + r;
        atomicAdd(&rowsum[grow], s);
      }
    }

  if (!diag) {
#pragma unroll
    for (int n = 0; n < 4; ++n) {
      float c = colpart[n];
      c += __shfl_xor(c, 16);
      c += __shfl_xor(c, 32);
      if (r4 == 0) {
        int gcol = bj * BN + wn * 64 + n * 16 + cl;
        atomicAdd(&rowsum[gcol], c);
      }
    }
  }
}

// ---- Kernel 3: finalize loss ---------------------------------------------
__global__ __launch_bounds__(256) void finalize_kernel(
    const float* __restrict__ rowsum, const float* __restrict__ posp,
    float* __restrict__ out) {
  __shared__ float ws4[4];
  int tid = threadIdx.x;
  float v = 0.f;
  for (int i = tid; i < NROWS; i += 256) v += logf(rowsum[i]);
  for (int i = tid; i < 1024; i += 256) v -= posp[i];
#pragma unroll
  for (int off = 32; off; off >>= 1) v += __shfl_xor(v, off);
  if ((tid & 63) == 0) ws4[tid >> 6] = v;
  __syncthreads();
  if (tid == 0)
    out[0] = (ws4[0] + ws4[1] + ws4[2] + ws4[3]) / (float)NROWS;
}

extern "C" void kernel_launch(void* const* d_in, const int* in_sizes, int n_in,
                              void* d_out, int out_size, void* d_ws,
                              size_t ws_size, hipStream_t stream) {
  const float* zi = (const float*)d_in[0];
  const float* zj = (const float*)d_in[1];
  float* out      = (float*)d_out;

  char* ws          = (char*)d_ws;
  unsigned short* p = (unsigned short*)ws;                        // 8 MB bf16
  float* rowsum     = (float*)(ws + (size_t)NROWS * DIM * 2);     // 32 KB
  float* posp       = rowsum + NROWS;                             // 4 KB

  normalize_pos_kernel<<<NB / 4, 256, 0, stream>>>(zi, zj, p, rowsum, posp);
  simexp_kernel<<<NBLK, 256, 0, stream>>>(p, rowsum);
  finalize_kernel<<<1, 256, 0, stream>>>(rowsum, posp, out);
}

// Round 4
// 97.457 us; speedup vs baseline: 1.3502x; 1.0992x over previous
//
#include <hip/hip_runtime.h>
#include <hip/hip_bf16.h>
#include <stdint.h>

#define NB    4096
#define NROWS 8192
#define DIM   512
#define BM    128
#define BN    128
#define BK    32
#define NKS   (DIM / BK)              // 16 K-steps
#define NBLK  2176                    // 8 XCDs x 272 (96 early-exit)

typedef __attribute__((ext_vector_type(8))) short          bf16x8;
typedef __attribute__((ext_vector_type(4))) float          f32x4;
typedef __attribute__((ext_vector_type(8))) unsigned short u16x8;

__device__ __forceinline__ unsigned short f2bf(float f) {
  uint32_t u = __float_as_uint(f);
  u += 0x7fffu + ((u >> 16) & 1u);   // round-to-nearest-even
  return (unsigned short)(u >> 16);
}

__device__ __forceinline__ float bf2f(unsigned short h) {
  return __uint_as_float(((uint32_t)h) << 16);
}

__device__ __forceinline__ void gload_lds16(const void* g, void* l) {
  __builtin_amdgcn_global_load_lds(
      (const __attribute__((address_space(1))) void*)g,
      (__attribute__((address_space(3))) void*)l, 16, 0, 0);
}

// ---- Kernel 1: normalize rows -> bf16 P, fused pos partials, zero rowsum --
__global__ __launch_bounds__(256) void normalize_pos_kernel(
    const float* __restrict__ zi, const float* __restrict__ zj,
    unsigned short* __restrict__ p, float* __restrict__ rowsum,
    float* __restrict__ posp) {
  __shared__ float ws4[4];
  const int wave = threadIdx.x >> 6;
  const int lane = threadIdx.x & 63;
  const int i    = blockIdx.x * 4 + wave;          // 0..4095

  int gt = blockIdx.x * 256 + threadIdx.x;
  if (gt < NROWS) rowsum[gt] = 0.f;

  const float4* sa = (const float4*)(zi + (size_t)i * DIM);
  const float4* sb = (const float4*)(zj + (size_t)i * DIM);
  float4 a0 = sa[lane * 2], a1 = sa[lane * 2 + 1];
  float4 b0 = sb[lane * 2], b1 = sb[lane * 2 + 1];
  float va[8] = {a0.x, a0.y, a0.z, a0.w, a1.x, a1.y, a1.z, a1.w};
  float vb[8] = {b0.x, b0.y, b0.z, b0.w, b1.x, b1.y, b1.z, b1.w};
  float ssa = 0.f, ssb = 0.f;
#pragma unroll
  for (int j = 0; j < 8; ++j) { ssa += va[j] * va[j]; ssb += vb[j] * vb[j]; }
#pragma unroll
  for (int off = 32; off; off >>= 1) {
    ssa += __shfl_xor(ssa, off);
    ssb += __shfl_xor(ssb, off);
  }
  float inva = rsqrtf(ssa), invb = rsqrtf(ssb);
  u16x8 ha, hb;
#pragma unroll
  for (int j = 0; j < 8; ++j) { ha[j] = f2bf(va[j] * inva); hb[j] = f2bf(vb[j] * invb); }
  *(u16x8*)(p + (size_t)i * DIM + lane * 8)        = ha;
  *(u16x8*)(p + (size_t)(i + NB) * DIM + lane * 8) = hb;

  float d = 0.f;
#pragma unroll
  for (int j = 0; j < 8; ++j) d += bf2f(ha[j]) * bf2f(hb[j]);
#pragma unroll
  for (int off = 32; off; off >>= 1) d += __shfl_xor(d, off);
  if (lane == 0) ws4[wave] = d;
  __syncthreads();
  if (threadIdx.x == 0)
    posp[blockIdx.x] = 4.0f * (ws4[0] + ws4[1] + ws4[2] + ws4[3]);
}

// ---- Kernel 2: symmetric fused S = 2*P*P^T -> exp -> row+col sums ---------
// Upper-triangle tile grid partitioned into 4x4 supertiles of 16x16 tiles
// (XCD x = blockIdx.x%8 owns ~4MB == its L2).
// Depth-2 pipeline, 3 rotating LDS buffers: STAGE(t+2) -> vmcnt(8) (tile t
// landed; t+1,t+2 in flight across barriers) -> barrier -> ds_read(t) ->
// lgkmcnt(0) -> barrier -> MFMA.
__global__ __launch_bounds__(256) void simexp_kernel(
    const unsigned short* __restrict__ p, float* __restrict__ rowsum) {
  __shared__ unsigned short As[3][BM * BK];   // 3 x 8 KB
  __shared__ unsigned short Bs[3][BM * BK];   // 3 x 8 KB

  const int x = blockIdx.x & 7;          // XCD (round-robin heuristic)
  const int l = blockIdx.x >> 3;         // 0..271 local index
  int bi, bj;
  if (x < 6) {
    if (l >= 256) return;                // uniform early-exit, before barriers
    const int sqi[6] = {0, 0, 0, 1, 1, 2};
    const int sqj[6] = {1, 2, 3, 2, 3, 3};
    bi = sqi[x] * 16 + (l >> 4);
    bj = sqj[x] * 16 + (l & 15);
  } else {
    int s  = (x == 6) ? 0 : 2;
    int ll = l;
    if (ll >= 136) { ll -= 136; s += 1; }
    int i = 0;
    while ((i + 1) * (33 - (i + 1)) / 2 <= ll) ++i;
    int j = i + (ll - i * (33 - i) / 2);
    bi = s * 16 + i;
    bj = s * 16 + j;
  }
  const bool diag = (bi == bj);

  const int tid  = threadIdx.x;
  const int wave = tid >> 6;
  const int lane = tid & 63;
  const int wm   = wave >> 1;
  const int wn   = wave & 1;

  f32x4 acc[4][4] = {};

  const int srow   = tid >> 2;
  const int schunk = tid & 3;
  const unsigned short* pa = p + (size_t)(bi * BM) * DIM;
  const unsigned short* pb = p + (size_t)(bj * BN) * DIM;

  const int frow = lane & 15;
  const int kc   = lane >> 4;

  // precompute ds_read byte offsets (swizzled), invariant over K
  int offA[4], offB[4];
#pragma unroll
  for (int m = 0; m < 4; ++m) {
    int row = wm * 64 + m * 16 + frow;
    offA[m] = row * 64 + (kc ^ ((row >> 1) & 3)) * 16;
  }
#pragma unroll
  for (int n = 0; n < 4; ++n) {
    int row = wn * 64 + n * 16 + frow;
    offB[n] = row * 64 + (kc ^ ((row >> 1) & 3)) * 16;
  }

#define STAGE(buf, k0)                                                        \
  {                                                                           \
    _Pragma("unroll")                                                         \
    for (int h = 0; h < 2; ++h) {                                             \
      int r      = h * 64 + srow;                                             \
      int gchunk = schunk ^ ((r >> 1) & 3);                                   \
      gload_lds16(pa + (size_t)r * DIM + (k0) + gchunk * 8,                   \
                  (char*)As[buf] + h * 4096 + wave * 1024);                   \
      gload_lds16(pb + (size_t)r * DIM + (k0) + gchunk * 8,                   \
                  (char*)Bs[buf] + h * 4096 + wave * 1024);                   \
    }                                                                         \
  }

#define LOAD_FRAGS(buf)                                                       \
  {                                                                           \
    const char* ba = (const char*)As[buf];                                    \
    const char* bb = (const char*)Bs[buf];                                    \
    _Pragma("unroll")                                                         \
    for (int m = 0; m < 4; ++m) af[m] = *(const bf16x8*)(ba + offA[m]);       \
    _Pragma("unroll")                                                         \
    for (int n = 0; n < 4; ++n) bf_[n] = *(const bf16x8*)(bb + offB[n]);      \
  }

#define DO_MFMA()                                                             \
  {                                                                           \
    _Pragma("unroll")                                                         \
    for (int m = 0; m < 4; ++m)                                               \
      _Pragma("unroll")                                                       \
      for (int n = 0; n < 4; ++n)                                             \
        acc[m][n] = __builtin_amdgcn_mfma_f32_16x16x32_bf16(                  \
            af[m], bf_[n], acc[m][n], 0, 0, 0);                               \
  }

  // prologue: tiles 0 and 1 in flight
  STAGE(0, 0);
  STAGE(1, BK);
  int rb = 0;   // read buffer = tile t % 3
  for (int t = 0; t < NKS; ++t) {
    bf16x8 af[4], bf_[4];
    if (t + 2 < NKS) {
      int sb = (rb + 2 >= 3) ? rb - 1 : rb + 2;   // (t+2) % 3
      STAGE(sb, (t + 2) * BK);
      asm volatile("s_waitcnt vmcnt(8)" ::: "memory");   // tile t landed
    } else if (t + 1 < NKS) {
      asm volatile("s_waitcnt vmcnt(4)" ::: "memory");
    } else {
      asm volatile("s_waitcnt vmcnt(0)" ::: "memory");
    }
    __builtin_amdgcn_s_barrier();                        // all waves' tile t in
    LOAD_FRAGS(rb);
    asm volatile("s_waitcnt lgkmcnt(0)" ::: "memory");   // my reads done
    if (t + 1 < NKS) __builtin_amdgcn_s_barrier();       // safe to overwrite rb
    DO_MFMA();
    rb = (rb + 1 == 3) ? 0 : rb + 1;
  }

  // epilogue: e = exp(2s); rowsum[row] += e; rowsum[col] += e if off-diag
  const int r4 = lane >> 4;   // C/D: col = lane&15, row = (lane>>4)*4 + reg
  const int cl = lane & 15;

  float rowpart[4][4];
  float colpart[4] = {0.f, 0.f, 0.f, 0.f};

  if (diag) {
#pragma unroll
    for (int m = 0; m < 4; ++m)
#pragma unroll
      for (int r = 0; r < 4; ++r) {
        int grow = bi * BM + wm * 64 + m * 16 + r4 * 4 + r;
        float s = 0.f;
#pragma unroll
        for (int n = 0; n < 4; ++n) {
          int gcol = bj * BN + wn * 64 + n * 16 + cl;
          float e  = __expf(2.0f * acc[m][n][r]);
          s += (grow == gcol) ? 0.f : e;
        }
        rowpart[m][r] = s;
      }
  } else {
#pragma unroll
    for (int m = 0; m < 4; ++m)
#pragma unroll
      for (int r = 0; r < 4; ++r) {
        float s = 0.f;
#pragma unroll
        for (int n = 0; n < 4; ++n) {
          float e = __expf(2.0f * acc[m][n][r]);
          s += e;
          colpart[n] += e;
        }
        rowpart[m][r] = s;
      }
  }

#pragma unroll
  for (int m = 0; m < 4; ++m)
#pragma unroll
    for (int r = 0; r < 4; ++r) {
      float s = rowpart[m][r];
      s += __shfl_xor(s, 1);
      s += __shfl_xor(s, 2);
      s += __shfl_xor(s, 4);
      s += __shfl_xor(s, 8);
      if (cl == 0) {
        int grow = bi * BM + wm * 64 + m * 16 + r4 * 4 + r;
        atomicAdd(&rowsum[grow], s);
      }
    }

  if (!diag) {
#pragma unroll
    for (int n = 0; n < 4; ++n) {
      float c = colpart[n];
      c += __shfl_xor(c, 16);
      c += __shfl_xor(c, 32);
      if (r4 == 0) {
        int gcol = bj * BN + wn * 64 + n * 16 + cl;
        atomicAdd(&rowsum[gcol], c);
      }
    }
  }
}

// ---- Kernel 3: finalize loss ---------------------------------------------
__global__ __launch_bounds__(256) void finalize_kernel(
    const float* __restrict__ rowsum, const float* __restrict__ posp,
    float* __restrict__ out) {
  __shared__ float ws4[4];
  int tid = threadIdx.x;
  float v = 0.f;
  for (int i = tid; i < NROWS; i += 256) v += logf(rowsum[i]);
  for (int i = tid; i < 1024; i += 256) v -= posp[i];
#pragma unroll
  for (int off = 32; off; off >>= 1) v += __shfl_xor(v, off);
  if ((tid & 63) == 0) ws4[tid >> 6] = v;
  __syncthreads();
  if (tid == 0)
    out[0] = (ws4[0] + ws4[1] + ws4[2] + ws4[3]) / (float)NROWS;
}

extern "C" void kernel_launch(void* const* d_in, const int* in_sizes, int n_in,
                              void* d_out, int out_size, void* d_ws,
                              size_t ws_size, hipStream_t stream) {
  const float* zi = (const float*)d_in[0];
  const float* zj = (const float*)d_in[1];
  float* out      = (float*)d_out;

  char* ws          = (char*)d_ws;
  unsigned short* p = (unsigned short*)ws;                        // 8 MB bf16
  float* rowsum     = (float*)(ws + (size_t)NROWS * DIM * 2);     // 32 KB
  float* posp       = rowsum + NROWS;                             // 4 KB

  normalize_pos_kernel<<<NB / 4, 256, 0, stream>>>(zi, zj, p, rowsum, posp);
  simexp_kernel<<<NBLK, 256, 0, stream>>>(p, rowsum);
  finalize_kernel<<<1, 256, 0, stream>>>(rowsum, posp, out);
}